// Round 2
// baseline (219.001 us; speedup 1.0000x reference)
//
#include <hip/hip_runtime.h>

// SpaceCarverGridSampler: nearest grid-sample with 3x3 hole-fix search.
// depth: (B=8, C=1, H=512, W=512) f32, grid: (B, 1024, 1024, 2) f32
// out:   (B, 1, 1024, 1024) f32
//
// Round 2: latency-bound fix — all 9 candidate gathers issued unconditionally
// and independently (batched loads, single waitcnt), branch-free priority
// select; 2 pixels per thread (float4 grid load, float2 out store) for 18
// loads in flight per thread.

#define SC_B  8
#define SC_H  512
#define SC_W  512
#define SC_HO 1024
#define SC_WO 1024

__device__ __forceinline__ float sample_one(const float* __restrict__ img,
                                            float gx, float gy)
{
    // unnormalize, align_corners=True, exact fp32 order as reference
    float x = (gx + 1.0f) * 0.5f * (float)(SC_W - 1);
    float y = (gy + 1.0f) * 0.5f * (float)(SC_H - 1);

    // jnp.round = round-half-to-even = rintf under default RNE mode
    int ix = (int)rintf(x);
    int iy = (int)rintf(y);

    // center first, then ring in row-major (dy,dx) order
    const int dys[9] = { 0, -1, -1, -1,  0, 0,  1, 1, 1 };
    const int dxs[9] = { 0, -1,  0,  1, -1, 1, -1, 0, 1 };

    float v[9];
    bool  inb[9];
    #pragma unroll
    for (int k = 0; k < 9; ++k) {
        int cy = iy + dys[k];
        int cx = ix + dxs[k];
        inb[k] = (cy >= 0) & (cy < SC_H) & (cx >= 0) & (cx < SC_W);
        int cyc = min(max(cy, 0), SC_H - 1);
        int cxc = min(max(cx, 0), SC_W - 1);
        v[k] = img[cyc * SC_W + cxc];   // unconditional, independent loads
    }

    // reverse-priority branch-free select: lowest k (center) wins
    float result = 0.0f;
    #pragma unroll
    for (int k = 8; k >= 0; --k) {
        bool valid = inb[k] & (v[k] != 0.0f);
        result = valid ? v[k] : result;
    }
    return result;
}

__global__ __launch_bounds__(256) void SpaceCarverGridSamplerModule_kernel(
    const float* __restrict__ depth,
    const float* __restrict__ grid,
    float* __restrict__ out,
    int total_pairs)
{
    int t = blockIdx.x * blockDim.x + threadIdx.x;
    if (t >= total_pairs) return;

    int idx0 = t * 2;               // first pixel of the pair
    int b = idx0 >> 20;             // npix = HO*WO = 1<<20

    // coalesced 16B grid load: two (x,y) pairs
    float4 g = reinterpret_cast<const float4*>(grid)[t];

    const float* __restrict__ img = depth + (size_t)b * (SC_H * SC_W);

    float r0 = sample_one(img, g.x, g.y);
    float r1 = sample_one(img, g.z, g.w);

    reinterpret_cast<float2*>(out)[t] = make_float2(r0, r1);
}

extern "C" void kernel_launch(void* const* d_in, const int* in_sizes, int n_in,
                              void* d_out, int out_size, void* d_ws, size_t ws_size,
                              hipStream_t stream) {
    const float* depth = (const float*)d_in[0];  // (8,1,512,512)
    const float* grid  = (const float*)d_in[1];  // (8,1024,1024,2)
    float* out = (float*)d_out;                  // (8,1,1024,1024)

    int total_pairs = out_size / 2;  // 2 pixels per thread; out_size = 8*1024*1024 (even)
    dim3 block(256);
    dim3 gridDim((total_pairs + block.x - 1) / block.x);
    SpaceCarverGridSamplerModule_kernel<<<gridDim, block, 0, stream>>>(depth, grid, out, total_pairs);
}

// Round 3
// 145.192 us; speedup vs baseline: 1.5084x; 1.5084x over previous
//
#include <hip/hip_runtime.h>

// SpaceCarverGridSampler: nearest grid-sample with 3x3 hole-fix search.
// depth: (B=8, C=1, H=512, W=512) f32, grid: (B, 1024, 1024, 2) f32
// out:   (B, 1, 1024, 1024) f32
//
// Round 3: the 3x3 fix-search is a pure function of the SOURCE pixel, not the
// output pixel. Pass 1 precomputes fixedPad[b][y][x] (padded domain
// y,x in [-1,512]) = first-valid-candidate in reference priority order.
// Pass 2 does ONE gather per output pixel (vs 9 in round 2 / ~1.3 serialized
// in round 1), branch-free, 4 px/thread. This cuts L2 gather transactions
// ~9x vs round 2 and removes the serialized dependent-load chain of round 1.

#define SC_B  8
#define SC_H  512
#define SC_W  512
#define SC_HO 1024
#define SC_WO 1024

// padded fixed image: rows/cols cover [-1, 512] -> 514 x 514, stride 516
#define FP_H  514
#define FP_W  514
#define FP_S  516
#define FP_BATCH (FP_H * FP_S)

// ---------------- Pass 1: build fixedPad ----------------
__global__ __launch_bounds__(256) void build_fixed_kernel(
    const float* __restrict__ depth,
    float* __restrict__ fixedPad)
{
    int b = blockIdx.y;
    int t = blockIdx.x * blockDim.x + threadIdx.x;
    if (t >= FP_H * FP_W) return;
    int py = t / FP_W;       // 0..513
    int px = t - py * FP_W;  // 0..513
    int y = py - 1;          // -1..512  (source-center coord)
    int x = px - 1;

    const float* __restrict__ img = depth + (size_t)b * (SC_H * SC_W);

    // center first, then ring in row-major (dy,dx) order
    const int dys[9] = { 0, -1, -1, -1,  0, 0,  1, 1, 1 };
    const int dxs[9] = { 0, -1,  0,  1, -1, 1, -1, 0, 1 };

    float v[9];
    bool  inb[9];
    #pragma unroll
    for (int k = 0; k < 9; ++k) {
        int cy = y + dys[k];
        int cx = x + dxs[k];
        inb[k] = (cy >= 0) & (cy < SC_H) & (cx >= 0) & (cx < SC_W);
        int cyc = min(max(cy, 0), SC_H - 1);
        int cxc = min(max(cx, 0), SC_W - 1);
        v[k] = img[cyc * SC_W + cxc];   // coalesced neighborhoods, L1-friendly
    }

    // reverse-priority branch-free select: lowest k (center) wins
    float result = 0.0f;
    #pragma unroll
    for (int k = 8; k >= 0; --k) {
        bool valid = inb[k] & (v[k] != 0.0f);
        result = valid ? v[k] : result;
    }

    fixedPad[(size_t)b * FP_BATCH + py * FP_S + px] = result;
}

// ---------------- Pass 2: sample (1 gather per pixel, 4 px/thread) ----------
__device__ __forceinline__ float sample_fixed(const float* __restrict__ fp,
                                              float gx, float gy)
{
    // unnormalize, align_corners=True, exact fp32 order as reference
    float x = (gx + 1.0f) * 0.5f * (float)(SC_W - 1);
    float y = (gy + 1.0f) * 0.5f * (float)(SC_H - 1);
    int ix = (int)rintf(x);   // jnp.round = RNE = rintf
    int iy = (int)rintf(y);

    // any candidate in-bounds iff ix in [-1, W] and iy in [-1, H]
    bool inrange = (ix >= -1) & (ix <= SC_W) & (iy >= -1) & (iy <= SC_H);
    int px = min(max(ix + 1, 0), FP_W - 1);
    int py = min(max(iy + 1, 0), FP_H - 1);
    float v = fp[py * FP_S + px];
    return inrange ? v : 0.0f;
}

__global__ __launch_bounds__(256) void sample_kernel(
    const float* __restrict__ fixedPad,
    const float* __restrict__ grid,
    float* __restrict__ out,
    int total_quads)
{
    int t = blockIdx.x * blockDim.x + threadIdx.x;
    if (t >= total_quads) return;

    int p0 = t * 4;          // first pixel of the quad; all 4 in same batch
    int b = p0 >> 20;        // npix per batch = 1<<20

    const float4* g4 = reinterpret_cast<const float4*>(grid);
    float4 gA = g4[2 * t];       // px p0, p0+1
    float4 gB = g4[2 * t + 1];   // px p0+2, p0+3

    const float* __restrict__ fp = fixedPad + (size_t)b * FP_BATCH;

    float r0 = sample_fixed(fp, gA.x, gA.y);
    float r1 = sample_fixed(fp, gA.z, gA.w);
    float r2 = sample_fixed(fp, gB.x, gB.y);
    float r3 = sample_fixed(fp, gB.z, gB.w);

    reinterpret_cast<float4*>(out)[t] = make_float4(r0, r1, r2, r3);
}

// ---------------- Fallback (ws too small): round-1 style ----------------
__global__ __launch_bounds__(256) void fallback_kernel(
    const float* __restrict__ depth,
    const float* __restrict__ grid,
    float* __restrict__ out,
    int total)
{
    int idx = blockIdx.x * blockDim.x + threadIdx.x;
    if (idx >= total) return;
    int b = idx >> 20;
    float2 g = reinterpret_cast<const float2*>(grid)[idx];
    float x = (g.x + 1.0f) * 0.5f * (float)(SC_W - 1);
    float y = (g.y + 1.0f) * 0.5f * (float)(SC_H - 1);
    int ix = (int)rintf(x);
    int iy = (int)rintf(y);
    const float* __restrict__ img = depth + (size_t)b * (SC_H * SC_W);
    const int dys[9] = { 0, -1, -1, -1,  0, 0,  1, 1, 1 };
    const int dxs[9] = { 0, -1,  0,  1, -1, 1, -1, 0, 1 };
    float result = 0.0f;
    #pragma unroll
    for (int k = 0; k < 9; ++k) {
        int cy = iy + dys[k];
        int cx = ix + dxs[k];
        if (cy >= 0 && cy < SC_H && cx >= 0 && cx < SC_W) {
            float v = img[cy * SC_W + cx];
            if (v != 0.0f) { result = v; break; }
        }
    }
    out[idx] = result;
}

extern "C" void kernel_launch(void* const* d_in, const int* in_sizes, int n_in,
                              void* d_out, int out_size, void* d_ws, size_t ws_size,
                              hipStream_t stream) {
    const float* depth = (const float*)d_in[0];  // (8,1,512,512)
    const float* grid  = (const float*)d_in[1];  // (8,1024,1024,2)
    float* out = (float*)d_out;                  // (8,1,1024,1024)

    size_t need = (size_t)SC_B * FP_BATCH * sizeof(float);  // ~8.5 MB
    if (ws_size >= need) {
        float* fixedPad = (float*)d_ws;

        // Pass 1: 514*514 px per batch
        int per_batch = FP_H * FP_W;
        dim3 b1(256);
        dim3 g1((per_batch + b1.x - 1) / b1.x, SC_B);
        build_fixed_kernel<<<g1, b1, 0, stream>>>(depth, fixedPad);

        // Pass 2: 4 px/thread
        int total_quads = out_size / 4;
        dim3 b2(256);
        dim3 g2((total_quads + b2.x - 1) / b2.x);
        sample_kernel<<<g2, b2, 0, stream>>>(fixedPad, grid, out, total_quads);
    } else {
        int total = out_size;
        dim3 block(256);
        dim3 gridDim((total + block.x - 1) / block.x);
        fallback_kernel<<<gridDim, block, 0, stream>>>(depth, grid, out, total);
    }
}

// Round 4
// 144.144 us; speedup vs baseline: 1.5193x; 1.0073x over previous
//
#include <hip/hip_runtime.h>

// SpaceCarverGridSampler: nearest grid-sample with 3x3 hole-fix search.
// depth: (B=8, C=1, H=512, W=512) f32, grid: (B, 1024, 1024, 2) f32
// out:   (B, 1, 1024, 1024) f32
//
// Round 4: pass 2's random gathers were missing per-XCD L2 because every XCD
// touched all 8 batches' fixedPad tables (8.5 MB > 4 MiB L2). Swizzle
// batch = blockIdx.x & 7 so (with round-robin block->XCD dispatch) each XCD
// gathers from ONE batch's 1.06 MB table -> L2-resident. 8 px/thread with
// k-strided coalesced float4 grid loads for more loads in flight.

#define SC_B  8
#define SC_H  512
#define SC_W  512
#define SC_HO 1024
#define SC_WO 1024

// padded fixed image: rows/cols cover [-1, 512] -> 514 x 514, stride 516
#define FP_H  514
#define FP_W  514
#define FP_S  516
#define FP_BATCH (FP_H * FP_S)

// ---------------- Pass 1: build fixedPad ----------------
__global__ __launch_bounds__(256) void build_fixed_kernel(
    const float* __restrict__ depth,
    float* __restrict__ fixedPad)
{
    int b = blockIdx.y;
    int t = blockIdx.x * blockDim.x + threadIdx.x;
    if (t >= FP_H * FP_W) return;
    int py = t / FP_W;       // 0..513
    int px = t - py * FP_W;  // 0..513
    int y = py - 1;          // -1..512  (source-center coord)
    int x = px - 1;

    const float* __restrict__ img = depth + (size_t)b * (SC_H * SC_W);

    // center first, then ring in row-major (dy,dx) order
    const int dys[9] = { 0, -1, -1, -1,  0, 0,  1, 1, 1 };
    const int dxs[9] = { 0, -1,  0,  1, -1, 1, -1, 0, 1 };

    float v[9];
    bool  inb[9];
    #pragma unroll
    for (int k = 0; k < 9; ++k) {
        int cy = y + dys[k];
        int cx = x + dxs[k];
        inb[k] = (cy >= 0) & (cy < SC_H) & (cx >= 0) & (cx < SC_W);
        int cyc = min(max(cy, 0), SC_H - 1);
        int cxc = min(max(cx, 0), SC_W - 1);
        v[k] = img[cyc * SC_W + cxc];   // coalesced neighborhoods, L1-friendly
    }

    // reverse-priority branch-free select: lowest k (center) wins
    float result = 0.0f;
    #pragma unroll
    for (int k = 8; k >= 0; --k) {
        bool valid = inb[k] & (v[k] != 0.0f);
        result = valid ? v[k] : result;
    }

    fixedPad[(size_t)b * FP_BATCH + py * FP_S + px] = result;
}

// ---------------- Pass 2: sample (1 L2-local gather per pixel) --------------
__device__ __forceinline__ float sample_fixed(const float* __restrict__ fp,
                                              float gx, float gy)
{
    // unnormalize, align_corners=True, exact fp32 order as reference
    float x = (gx + 1.0f) * 0.5f * (float)(SC_W - 1);
    float y = (gy + 1.0f) * 0.5f * (float)(SC_H - 1);
    int ix = (int)rintf(x);   // jnp.round = RNE = rintf
    int iy = (int)rintf(y);

    // any candidate in-bounds iff ix in [-1, W] and iy in [-1, H]
    bool inrange = (ix >= -1) & (ix <= SC_W) & (iy >= -1) & (iy <= SC_H);
    int px = min(max(ix + 1, 0), FP_W - 1);
    int py = min(max(iy + 1, 0), FP_H - 1);
    float v = fp[py * FP_S + px];
    return inrange ? v : 0.0f;
}

// Layout: px-per-batch = 1<<20; grid float4s per batch = 1<<19.
// Block = 256 threads x 4 float4s (8 px) = 1024 float4s/block.
// Blocks per batch = 512; total blocks = 4096.
// batch = blockIdx.x & 7  -> XCD-affine (round-robin dispatch heuristic).
__global__ __launch_bounds__(256) void sample_kernel(
    const float* __restrict__ fixedPad,
    const float* __restrict__ grid,
    float* __restrict__ out)
{
    int b     = blockIdx.x & 7;
    int local = blockIdx.x >> 3;            // 0..511 within batch
    int base4 = (b << 19) + local * 1024;   // global float4 index of block start

    const float4* __restrict__ g4 = reinterpret_cast<const float4*>(grid);
    float2* __restrict__ o2 = reinterpret_cast<float2*>(out);

    const float* __restrict__ fp = fixedPad + (size_t)b * FP_BATCH;

    // 4 coalesced float4 loads per thread (stride 256 between insts)
    float4 g[4];
    int j[4];
    #pragma unroll
    for (int k = 0; k < 4; ++k) {
        j[k] = base4 + threadIdx.x + (k << 8);
        g[k] = g4[j[k]];
    }

    #pragma unroll
    for (int k = 0; k < 4; ++k) {
        float r0 = sample_fixed(fp, g[k].x, g[k].y);   // px 2*j[k]
        float r1 = sample_fixed(fp, g[k].z, g[k].w);   // px 2*j[k]+1
        o2[j[k]] = make_float2(r0, r1);                // coalesced 8B store
    }
}

// ---------------- Fallback (ws too small): round-1 style ----------------
__global__ __launch_bounds__(256) void fallback_kernel(
    const float* __restrict__ depth,
    const float* __restrict__ grid,
    float* __restrict__ out,
    int total)
{
    int idx = blockIdx.x * blockDim.x + threadIdx.x;
    if (idx >= total) return;
    int b = idx >> 20;
    float2 g = reinterpret_cast<const float2*>(grid)[idx];
    float x = (g.x + 1.0f) * 0.5f * (float)(SC_W - 1);
    float y = (g.y + 1.0f) * 0.5f * (float)(SC_H - 1);
    int ix = (int)rintf(x);
    int iy = (int)rintf(y);
    const float* __restrict__ img = depth + (size_t)b * (SC_H * SC_W);
    const int dys[9] = { 0, -1, -1, -1,  0, 0,  1, 1, 1 };
    const int dxs[9] = { 0, -1,  0,  1, -1, 1, -1, 0, 1 };
    float result = 0.0f;
    #pragma unroll
    for (int k = 0; k < 9; ++k) {
        int cy = iy + dys[k];
        int cx = ix + dxs[k];
        if (cy >= 0 && cy < SC_H && cx >= 0 && cx < SC_W) {
            float v = img[cy * SC_W + cx];
            if (v != 0.0f) { result = v; break; }
        }
    }
    out[idx] = result;
}

extern "C" void kernel_launch(void* const* d_in, const int* in_sizes, int n_in,
                              void* d_out, int out_size, void* d_ws, size_t ws_size,
                              hipStream_t stream) {
    const float* depth = (const float*)d_in[0];  // (8,1,512,512)
    const float* grid  = (const float*)d_in[1];  // (8,1024,1024,2)
    float* out = (float*)d_out;                  // (8,1,1024,1024)

    size_t need = (size_t)SC_B * FP_BATCH * sizeof(float);  // ~8.5 MB
    if (ws_size >= need && out_size == (SC_B << 20)) {
        float* fixedPad = (float*)d_ws;

        // Pass 1: 514*514 px per batch
        int per_batch = FP_H * FP_W;
        dim3 b1(256);
        dim3 g1((per_batch + b1.x - 1) / b1.x, SC_B);
        build_fixed_kernel<<<g1, b1, 0, stream>>>(depth, fixedPad);

        // Pass 2: XCD-swizzled, 8 px/thread. 4096 blocks.
        dim3 b2(256);
        dim3 g2(4096);
        sample_kernel<<<g2, b2, 0, stream>>>(fixedPad, grid, out);
    } else {
        int total = out_size;
        dim3 block(256);
        dim3 gridDim((total + block.x - 1) / block.x);
        fallback_kernel<<<gridDim, block, 0, stream>>>(depth, grid, out, total);
    }
}